// Round 1
// 137.021 us; speedup vs baseline: 1.1352x; 1.1352x over previous
//
#include <hip/hip_runtime.h>

#define EG   16000   // graph edges
#define BB   32      // batch
#define SIZE 16000   // feature length (1000 blocks * 16)

// ---- kernel 1: write reparameterized bias into out, zero the kl scalar ----
// out[b*SIZE + r] = eb[r]*exp(blv[r]) + bm[r]
__global__ __launch_bounds__(256) void init_out_kernel(
    const float* __restrict__ bm, const float* __restrict__ blv,
    const float* __restrict__ eb, float* __restrict__ out)
{
    int r = blockIdx.x * 256 + threadIdx.x;   // feature index
    int b = blockIdx.y;                        // batch index
    if (r < SIZE) {
        float bias = eb[r] * __expf(blv[r]) + bm[r];
        out[b * SIZE + r] = bias;
    }
    if (blockIdx.x == 0 && blockIdx.y == 0 && threadIdx.x == 0)
        out[BB * SIZE] = 0.0f;                 // kl scalar
}

// ---- kernel 2: one workgroup per edge, scatter with HW f32 atomics ----
// Edge e contributes, for all b, j:  out[b, t0*16+j] += sum_i v[i][j] * x[b, t1*16+i]
// Thread t owns (b0 = t>>4, j = t&15) and (b0+16, j): 32 FMAs + 2 atomics.
__global__ __launch_bounds__(256) void edge_kernel(
    const float* __restrict__ wm, const float* __restrict__ wlv,
    const float* __restrict__ ew, const float* __restrict__ x,
    const int* __restrict__ rows, const int* __restrict__ cols,
    float* __restrict__ out)
{
    __shared__ float vt[256];   // vt[i*16+j] = sampled weight
    __shared__ float xs[512];   // xs[b*16+i] = x[b, t1*16+i]

    int e    = blockIdx.x;
    int tid  = threadIdx.x;
    int base = e << 8;

    int t0 = rows[base] >> 4;   // rows[e*256] = t0*16 (broadcast load)
    int t1 = cols[base] >> 4;   // cols[e*256] = t1*16

    // values = eps_w * exp(log_var) + mean  (reparameterization sample)
    vt[tid] = ew[base + tid] * __expf(wlv[base + tid]) + wm[base + tid];

    int j  = tid & 15;
    int b0 = tid >> 4;          // 0..15
    int xb = t1 << 4;
    xs[tid]       = x[ b0        * SIZE + xb + j];
    xs[tid + 256] = x[(b0 + 16)  * SIZE + xb + j];
    __syncthreads();

    float acc0 = 0.f, acc1 = 0.f;
    #pragma unroll
    for (int i = 0; i < 16; ++i) {
        float vv = vt[(i << 4) + j];            // broadcast (same addr per j-group)
        acc0 += vv * xs[((b0)      << 4) + i];  // broadcast
        acc1 += vv * xs[((b0 + 16) << 4) + i];
    }

    int r = (t0 << 4) + j;
    // unsafeAtomicAdd -> global_atomic_add_f32 (HW f32 atomic, no CAS loop)
    unsafeAtomicAdd(&out[ b0       * SIZE + r], acc0);
    unsafeAtomicAdd(&out[(b0 + 16) * SIZE + r], acc1);
}

extern "C" void kernel_launch(void* const* d_in, const int* in_sizes, int n_in,
                              void* d_out, int out_size, void* d_ws, size_t ws_size,
                              hipStream_t stream) {
    const float* x   = (const float*)d_in[0];
    const float* wm  = (const float*)d_in[1];
    const float* wlv = (const float*)d_in[2];
    const float* bm  = (const float*)d_in[3];
    const float* blv = (const float*)d_in[4];
    const float* ew  = (const float*)d_in[5];
    const float* eb  = (const float*)d_in[6];
    const int* rows  = (const int*)d_in[7];
    const int* cols  = (const int*)d_in[8];
    float* out = (float*)d_out;

    // bias init (also zeroes kl), then edge scatter
    init_out_kernel<<<dim3((SIZE + 255) / 256, BB), 256, 0, stream>>>(bm, blv, eb, out);
    edge_kernel<<<EG, 256, 0, stream>>>(wm, wlv, ew, x, rows, cols, out);
}